// Round 1
// baseline (814.816 us; speedup 1.0000x reference)
//
#include <hip/hip_runtime.h>
#include <math.h>

#define BATCH 8
#define NPTS 2048
#define KF 1024
#define PT 64
#define ETH 512

// ---------------- device helpers ----------------
__device__ __forceinline__ void mat3mul(const float* A, const float* Bm, float* C) {
#pragma unroll
  for (int i = 0; i < 3; ++i)
#pragma unroll
    for (int j = 0; j < 3; ++j)
      C[i*3+j] = A[i*3+0]*Bm[0*3+j] + A[i*3+1]*Bm[1*3+j] + A[i*3+2]*Bm[2*3+j];
}

// se3 exp matching the reference formulas exactly (f32, sin/cos path vs small path)
__device__ void se3_exp_dev(const float* x, float* R, float* p) {
  float wx = x[0], wy = x[1], wz = x[2];
  float vx = x[3], vy = x[4], vz = x[5];
  float t2 = wx*wx + wy*wy + wz*wz;
  float t = sqrtf(t2);
  float A, Bc, Cc;
  if (t < 1e-6f) {
    A  = 1.f - t2*(1.f/6.f);
    Bc = 0.5f - t2*(1.f/24.f);
    Cc = (1.f/6.f) - t2*(1.f/120.f);
  } else {
    float s = sinf(t), c = cosf(t);
    A  = s / t;
    Bc = (1.f - c) / t2;
    Cc = (t - s) / (t2 * t);
  }
  float W[9]  = {0.f, -wz, wy,  wz, 0.f, -wx,  -wy, wx, 0.f};
  float W2[9];
  mat3mul(W, W, W2);
#pragma unroll
  for (int i = 0; i < 9; ++i) {
    float I = (i == 0 || i == 4 || i == 8) ? 1.f : 0.f;
    R[i] = I + A*W[i] + Bc*W2[i];
  }
  float V[9];
#pragma unroll
  for (int i = 0; i < 9; ++i) {
    float I = (i == 0 || i == 4 || i == 8) ? 1.f : 0.f;
    V[i] = I + Bc*W[i] + Cc*W2[i];
  }
  p[0] = V[0]*vx + V[1]*vy + V[2]*vz;
  p[1] = V[3]*vx + V[4]*vy + V[5]*vz;
  p[2] = V[6]*vx + V[7]*vy + V[8]*vz;
}

// float atomic max; sign-split so it is exact for any mix of signs.
__device__ __forceinline__ void atomicMaxFloat(float* addr, float val) {
  if (__float_as_uint(val) >> 31) {
    atomicMin((unsigned int*)addr, __float_as_uint(val));   // negative: smaller uint = larger float
  } else {
    atomicMax((int*)addr, __float_as_int(val));             // nonnegative: int order = float order
  }
}

// ---------------- kernels ----------------
__global__ void means_kernel(const float* __restrict__ tgt, const float* __restrict__ src,
                             float* __restrict__ mean_tgt, float* __restrict__ mean_src) {
  int which = blockIdx.x & 1, b = blockIdx.x >> 1;
  const float* p = (which ? src : tgt) + (size_t)b*NPTS*3;
  float* m = (which ? mean_src : mean_tgt) + b*3;
  int t = threadIdx.x;
  float s0 = 0.f, s1 = 0.f, s2 = 0.f;
  for (int i = t; i < NPTS; i += 256) {
    s0 += p[i*3+0]; s1 += p[i*3+1]; s2 += p[i*3+2];
  }
  __shared__ float red[256][3];
  red[t][0] = s0; red[t][1] = s1; red[t][2] = s2;
  __syncthreads();
  for (int s = 128; s > 0; s >>= 1) {
    if (t < s) { red[t][0] += red[t+s][0]; red[t][1] += red[t+s][1]; red[t][2] += red[t+s][2]; }
    __syncthreads();
  }
  if (t == 0) {
    m[0] = red[0][0] * (1.f/NPTS);
    m[1] = red[0][1] * (1.f/NPTS);
    m[2] = red[0][2] * (1.f/NPTS);
  }
}

__global__ void setup_kernel(const float* __restrict__ dt, const float* __restrict__ W1,
                             const float* __restrict__ b1, const float* __restrict__ igt_twist,
                             float* __restrict__ feats, float* __restrict__ f1,
                             float* __restrict__ W1eff7, float* __restrict__ b1eff7,
                             float* __restrict__ W1effL, float* __restrict__ b1effL,
                             float* __restrict__ g_buf, float* __restrict__ igt_inv,
                             float* __restrict__ loss_out) {
  int t = threadIdx.x;
  for (int i = t; i < BATCH*7*KF; i += 256) feats[i] = -INFINITY;
  for (int i = t; i < BATCH*KF;   i += 256) f1[i]    = -INFINITY;
  for (int i = t; i < BATCH*192;  i += 256) W1effL[i] = W1[i % 192];
  for (int i = t; i < BATCH*64;   i += 256) b1effL[i] = b1[i & 63];
  if (t < 192) W1eff7[t] = W1[t];
  if (t < 64)  b1eff7[t] = b1[t];
  if (t < BATCH*16) {
    int i = t & 15;
    g_buf[t] = (i == 0 || i == 5 || i == 10 || i == 15) ? 1.f : 0.f;
  }
  if (t == 0) *loss_out = 0.f;
  if (t < 6) {
    float tw[6] = {0.f,0.f,0.f,0.f,0.f,0.f};
    tw[t] = -dt[t];
    float R[9], tr[3];
    se3_exp_dev(tw, R, tr);
    float* Wd = W1eff7 + (t+1)*192;
    for (int d = 0; d < 3; ++d)
      for (int c = 0; c < 64; ++c)
        Wd[d*64+c] = R[0*3+d]*W1[c] + R[1*3+d]*W1[64+c] + R[2*3+d]*W1[128+c];
    float* bd = b1eff7 + (t+1)*64;
    for (int c = 0; c < 64; ++c)
      bd[c] = b1[c] + tr[0]*W1[c] + tr[1]*W1[64+c] + tr[2]*W1[128+c];
  }
  if (t >= 32 && t < 32+BATCH) {
    int b = t - 32;
    float R[9], tr[3];
    se3_exp_dev(igt_twist + b*6, R, tr);
    float* inv = igt_inv + b*12;
    for (int r = 0; r < 3; ++r) {
      inv[r*4+0] = R[0*3+r];
      inv[r*4+1] = R[1*3+r];
      inv[r*4+2] = R[2*3+r];
      inv[r*4+3] = -(R[0*3+r]*tr[0] + R[1*3+r]*tr[1] + R[2*3+r]*tr[2]);
    }
  }
}

// Fused encode: layer1 (folded transform) -> layer2 -> layer3 + max over points.
// out[b][j][k] accumulated via atomicMaxFloat (init to -inf by caller).
__global__ __launch_bounds__(ETH) void encode_kernel(
    const float* __restrict__ pts, const float* __restrict__ mean,
    const float* __restrict__ W1e, const float* __restrict__ b1e,
    const float* __restrict__ W2, const float* __restrict__ b2,
    const float* __restrict__ W3, const float* __restrict__ b3,
    float* __restrict__ out, int NJ, int per_batch) {
  const int tile = blockIdx.x;
  const int j    = blockIdx.y;
  const int b    = blockIdx.z;
  const int t    = threadIdx.x;
  const int widx = per_batch ? b : j;

  __shared__ float s_pts[PT*3];       // centered points
  __shared__ float s_w1[192];         // folded W1 (3x64)
  __shared__ float s_b1[64];
  __shared__ float s_h2t[128*PT];     // h2 transposed: [c2][pt], 32 KB
  __shared__ float s_a[8*512];        // 16 KB: h1t[64][64] -> W3 slab[8][512] -> reduce buf[512][8]

  if (t < 192) {
    int d = t % 3;
    s_pts[t] = pts[((size_t)b*NPTS + tile*PT)*3 + t] - mean[b*3 + d];
    s_w1[t]  = W1e[widx*192 + t];
  } else if (t < 256) {
    s_b1[t-192] = b1e[widx*64 + (t-192)];
  }
  __syncthreads();

  // layer 1: h1t[c][pt] = relu(pt . W1e[:,c] + b1e[c])
  for (int e = t; e < 64*PT; e += ETH) {
    int c = e >> 6, pt = e & (PT-1);
    float acc = s_b1[c]
              + s_pts[pt*3+0]*s_w1[c]
              + s_pts[pt*3+1]*s_w1[64+c]
              + s_pts[pt*3+2]*s_w1[128+c];
    s_a[c*PT + pt] = fmaxf(acc, 0.f);
  }
  __syncthreads();

  // layer 2: h2t[c2][pt] = relu(h1[pt,:] . W2[:,c2] + b2[c2]); 4pt x 4c2 per thread
  {
    int pt0 = (t >> 5) * 4;
    int c20 = (t & 31) * 4;
    float acc[4][4];
#pragma unroll
    for (int i = 0; i < 4; ++i)
#pragma unroll
      for (int c = 0; c < 4; ++c) acc[i][c] = 0.f;
    for (int k = 0; k < 64; ++k) {
      float a0 = s_a[k*PT+pt0+0];
      float a1 = s_a[k*PT+pt0+1];
      float a2 = s_a[k*PT+pt0+2];
      float a3 = s_a[k*PT+pt0+3];
      const float4 w = *(const float4*)(W2 + k*128 + c20);
      acc[0][0] += a0*w.x; acc[0][1] += a0*w.y; acc[0][2] += a0*w.z; acc[0][3] += a0*w.w;
      acc[1][0] += a1*w.x; acc[1][1] += a1*w.y; acc[1][2] += a1*w.z; acc[1][3] += a1*w.w;
      acc[2][0] += a2*w.x; acc[2][1] += a2*w.y; acc[2][2] += a2*w.z; acc[2][3] += a2*w.w;
      acc[3][0] += a3*w.x; acc[3][1] += a3*w.y; acc[3][2] += a3*w.z; acc[3][3] += a3*w.w;
    }
    const float4 bb = *(const float4*)(b2 + c20);
    float bv[4] = {bb.x, bb.y, bb.z, bb.w};
#pragma unroll
    for (int i = 0; i < 4; ++i)
#pragma unroll
      for (int c = 0; c < 4; ++c)
        s_h2t[(c20+c)*PT + pt0+i] = fmaxf(acc[i][c] + bv[c], 0.f);
  }
  __syncthreads();   // h2t ready; all h1t reads done (s_a reusable)

  // layer 3: two 512-feature quadrants; 8pt x 8feat accumulators per thread
  const int pt0 = (t >> 6) * 8;
  const int fo  = (t & 63) * 8;
  const size_t outbase = ((size_t)b*NJ + j) * KF;
  for (int q = 0; q < 2; ++q) {
    float acc[8][8];
#pragma unroll
    for (int i = 0; i < 8; ++i)
#pragma unroll
      for (int c = 0; c < 8; ++c) acc[i][c] = 0.f;

    for (int k0 = 0; k0 < 128; k0 += 8) {
      __syncthreads();           // previous slab / reduce-buffer reads complete
#pragma unroll
      for (int ii = 0; ii < 2; ++ii) {
        int idx4 = t + ii*ETH;   // 0..1023 float4s
        int lin = idx4 * 4;
        int kk = lin >> 9, f = lin & 511;
        *(float4*)(s_a + lin) = *(const float4*)(W3 + (size_t)(k0+kk)*KF + q*512 + f);
      }
      __syncthreads();
#pragma unroll
      for (int kk = 0; kk < 8; ++kk) {
        const float4 a01 = *(const float4*)(s_h2t + (k0+kk)*PT + pt0);
        const float4 a23 = *(const float4*)(s_h2t + (k0+kk)*PT + pt0 + 4);
        const float4 w01 = *(const float4*)(s_a + kk*512 + fo);
        const float4 w23 = *(const float4*)(s_a + kk*512 + fo + 4);
        float aa[8] = {a01.x, a01.y, a01.z, a01.w, a23.x, a23.y, a23.z, a23.w};
        float ww[8] = {w01.x, w01.y, w01.z, w01.w, w23.x, w23.y, w23.z, w23.w};
#pragma unroll
        for (int i = 0; i < 8; ++i)
#pragma unroll
          for (int c = 0; c < 8; ++c)
            acc[i][c] += aa[i]*ww[c];
      }
    }
    // per-thread max over its 8 points
    float vmax[8];
#pragma unroll
    for (int c = 0; c < 8; ++c) {
      float m = acc[0][c];
#pragma unroll
      for (int i = 1; i < 8; ++i) m = fmaxf(m, acc[i][c]);
      vmax[c] = m;
    }
    __syncthreads();             // slab reads done; reuse s_a as reduce buffer [512][8]
    {
      int f3 = t & 63, pg = t >> 6;
#pragma unroll
      for (int c = 0; c < 8; ++c)
        s_a[(f3*8+c)*8 + pg] = vmax[c];
    }
    __syncthreads();
    {
      float m = s_a[t*8+0];
#pragma unroll
      for (int i = 1; i < 8; ++i) m = fmaxf(m, s_a[t*8+i]);
      m += b3[q*512 + t];
      atomicMaxFloat(out + outbase + q*512 + t, m);
    }
  }
}

__global__ void pinv_kernel(const float* __restrict__ feats, const float* __restrict__ dt,
                            float* __restrict__ pinv) {
  int b = blockIdx.x, t = threadIdx.x;
  const float* f0 = feats + (size_t)b*7*KF;
  const float* fj = f0 + KF;
  float idt[6];
#pragma unroll
  for (int i = 0; i < 6; ++i) idt[i] = 1.f / dt[i];
  float H[21];
#pragma unroll
  for (int i = 0; i < 21; ++i) H[i] = 0.f;
  for (int k = t; k < KF; k += 256) {
    float f0k = f0[k];
    float Jk[6];
#pragma unroll
    for (int i = 0; i < 6; ++i) Jk[i] = (f0k - fj[i*KF + k]) * idt[i];
    int idx = 0;
#pragma unroll
    for (int i = 0; i < 6; ++i)
#pragma unroll
      for (int jj = i; jj < 6; ++jj) H[idx++] += Jk[i]*Jk[jj];
  }
  __shared__ float red[256*21];
#pragma unroll
  for (int i = 0; i < 21; ++i) red[t*21+i] = H[i];
  __syncthreads();
  for (int s = 128; s > 0; s >>= 1) {
    if (t < s)
      for (int i = 0; i < 21; ++i) red[t*21+i] += red[(t+s)*21+i];
    __syncthreads();
  }
  __shared__ float s_hinv[36];
  if (t == 0) {
    double A[6][12];
    int idx = 0;
    for (int i = 0; i < 6; ++i)
      for (int jj = i; jj < 6; ++jj) { A[i][jj] = red[idx]; A[jj][i] = red[idx]; idx++; }
    for (int i = 0; i < 6; ++i)
      for (int jj = 0; jj < 6; ++jj) A[i][6+jj] = (i == jj) ? 1.0 : 0.0;
    for (int col = 0; col < 6; ++col) {
      int piv = col; double best = fabs(A[col][col]);
      for (int r2 = col+1; r2 < 6; ++r2) {
        double v = fabs(A[r2][col]);
        if (v > best) { best = v; piv = r2; }
      }
      if (piv != col)
        for (int jj = 0; jj < 12; ++jj) { double tmp = A[col][jj]; A[col][jj] = A[piv][jj]; A[piv][jj] = tmp; }
      double inv = 1.0 / A[col][col];
      for (int jj = 0; jj < 12; ++jj) A[col][jj] *= inv;
      for (int r2 = 0; r2 < 6; ++r2) if (r2 != col) {
        double f = A[r2][col];
        for (int jj = 0; jj < 12; ++jj) A[r2][jj] -= f * A[col][jj];
      }
    }
    for (int i = 0; i < 6; ++i)
      for (int jj = 0; jj < 6; ++jj) s_hinv[i*6+jj] = (float)A[i][6+jj];
  }
  __syncthreads();
  for (int k = t; k < KF; k += 256) {
    float f0k = f0[k];
    float Jk[6];
#pragma unroll
    for (int i = 0; i < 6; ++i) Jk[i] = (f0k - fj[i*KF + k]) * idt[i];
#pragma unroll
    for (int i = 0; i < 6; ++i) {
      float s = 0.f;
#pragma unroll
      for (int jj = 0; jj < 6; ++jj) s += s_hinv[i*6+jj] * Jk[jj];
      pinv[((size_t)b*6 + i)*KF + k] = s;
    }
  }
}

__global__ void update_kernel(const float* __restrict__ feats, const float* __restrict__ f1,
                              const float* __restrict__ pinv, float* __restrict__ g_buf,
                              const float* __restrict__ W1, const float* __restrict__ b1,
                              float* __restrict__ W1effL, float* __restrict__ b1effL,
                              float* __restrict__ f1r, float* __restrict__ r_out,
                              const float* __restrict__ mean_tgt, const float* __restrict__ mean_src,
                              float* __restrict__ est_g, int final_it) {
  int b = blockIdx.x, t = threadIdx.x;
  const float* f0  = feats + (size_t)b*7*KF;
  const float* f1b = f1 + (size_t)b*KF;
  float acc[6] = {0.f,0.f,0.f,0.f,0.f,0.f};
  for (int k = t; k < KF; k += 256) {
    float r = f1b[k] - f0[k];
    r_out[(size_t)b*KF + k] = r;
#pragma unroll
    for (int i = 0; i < 6; ++i) acc[i] += pinv[((size_t)b*6+i)*KF + k] * r;
  }
  __shared__ float red[256*6];
#pragma unroll
  for (int i = 0; i < 6; ++i) red[t*6+i] = acc[i];
  __syncthreads();
  for (int s = 128; s > 0; s >>= 1) {
    if (t < s)
      for (int i = 0; i < 6; ++i) red[t*6+i] += red[(t+s)*6+i];
    __syncthreads();
  }
  __shared__ float s_g[16];
  if (t == 0) {
    float dx[6];
#pragma unroll
    for (int i = 0; i < 6; ++i) dx[i] = -red[i];
    float R[9], p[3];
    se3_exp_dev(dx, R, p);
    float* g = g_buf + b*16;
    float gn[16];
    for (int r2 = 0; r2 < 3; ++r2)
      for (int c = 0; c < 4; ++c)
        gn[r2*4+c] = R[r2*3+0]*g[c] + R[r2*3+1]*g[4+c] + R[r2*3+2]*g[8+c] + p[r2]*g[12+c];
    gn[12] = 0.f; gn[13] = 0.f; gn[14] = 0.f; gn[15] = 1.f;
    for (int i = 0; i < 16; ++i) { g[i] = gn[i]; s_g[i] = gn[i]; }
    if (final_it) {
      const float* p0m = mean_tgt + b*3;
      const float* p1m = mean_src + b*3;
      float* e = est_g + b*12;
      for (int r2 = 0; r2 < 3; ++r2) {
        e[r2*4+0] = gn[r2*4+0];
        e[r2*4+1] = gn[r2*4+1];
        e[r2*4+2] = gn[r2*4+2];
        e[r2*4+3] = gn[r2*4+3]
                  - (gn[r2*4+0]*p1m[0] + gn[r2*4+1]*p1m[1] + gn[r2*4+2]*p1m[2])
                  + p0m[r2];
      }
    }
  }
  __syncthreads();
  if (!final_it) {
    for (int i = t; i < 192; i += 256) {
      int d = i >> 6, c = i & 63;
      W1effL[b*192 + i] = s_g[0*4+d]*W1[c] + s_g[1*4+d]*W1[64+c] + s_g[2*4+d]*W1[128+c];
    }
    for (int i = t; i < 64; i += 256)
      b1effL[b*64 + i] = b1[i] + s_g[3]*W1[i] + s_g[7]*W1[64+i] + s_g[11]*W1[128+i];
    for (int k = t; k < KF; k += 256) f1r[(size_t)b*KF + k] = -INFINITY;
  }
}

__global__ void loss_kernel(const float* __restrict__ p_src, const float* __restrict__ est_g,
                            const float* __restrict__ igt_inv, float* __restrict__ loss_out) {
  int b = blockIdx.y, tile = blockIdx.x, t = threadIdx.x;
  int n = tile*256 + t;
  const float* e = est_g + b*12;
  const float* v = igt_inv + b*12;
  const float* p = p_src + ((size_t)b*NPTS + n)*3;
  float px = p[0], py = p[1], pz = p[2];
  float s = 0.f;
#pragma unroll
  for (int r2 = 0; r2 < 3; ++r2) {
    float d1 = e[r2*4+0]*px + e[r2*4+1]*py + e[r2*4+2]*pz + e[r2*4+3];
    float d2 = v[r2*4+0]*px + v[r2*4+1]*py + v[r2*4+2]*pz + v[r2*4+3];
    s += fabsf(d1 - d2);
  }
  __shared__ float red[256];
  red[t] = s;
  __syncthreads();
  for (int st = 128; st > 0; st >>= 1) {
    if (t < st) red[t] += red[t+st];
    __syncthreads();
  }
  if (t == 0) atomicAdd(loss_out, red[0] * (1.f/((float)BATCH*NPTS*3)));
}

// ---------------- launcher ----------------
extern "C" void kernel_launch(void* const* d_in, const int* in_sizes, int n_in,
                              void* d_out, int out_size, void* d_ws, size_t ws_size,
                              hipStream_t stream) {
  const float* p_src     = (const float*)d_in[0];
  const float* p_tgt     = (const float*)d_in[1];
  const float* igt_twist = (const float*)d_in[2];
  const float* dt        = (const float*)d_in[3];
  const float* W1        = (const float*)d_in[4];
  const float* b1        = (const float*)d_in[5];
  const float* W2        = (const float*)d_in[6];
  const float* b2        = (const float*)d_in[7];
  const float* W3        = (const float*)d_in[8];
  const float* b3        = (const float*)d_in[9];
  float* out = (float*)d_out;

  float* ws = (float*)d_ws;
  float* mean_tgt = ws;  ws += BATCH*3;
  float* mean_src = ws;  ws += BATCH*3;
  float* W1eff7   = ws;  ws += 7*192;
  float* b1eff7   = ws;  ws += 7*64;
  float* feats    = ws;  ws += BATCH*7*KF;
  float* W1effL   = ws;  ws += BATCH*192;
  float* b1effL   = ws;  ws += BATCH*64;
  float* f1       = ws;  ws += BATCH*KF;
  float* g_buf    = ws;  ws += BATCH*16;
  float* pinvb    = ws;  ws += BATCH*6*KF;
  float* igt_inv  = ws;  ws += BATCH*12;
  float* est_g    = ws;  ws += BATCH*12;

  float* r_out    = out;
  float* loss_out = out + BATCH*KF;

  means_kernel<<<dim3(BATCH*2), 256, 0, stream>>>(p_tgt, p_src, mean_tgt, mean_src);
  setup_kernel<<<1, 256, 0, stream>>>(dt, W1, b1, igt_twist, feats, f1, W1eff7, b1eff7,
                                      W1effL, b1effL, g_buf, igt_inv, loss_out);
  // f0 (j=0) and the 6 twist-perturbed encodes (j=1..6), input q0 = p_tgt - p0_m
  encode_kernel<<<dim3(NPTS/PT, 7, BATCH), ETH, 0, stream>>>(
      p_tgt, mean_tgt, W1eff7, b1eff7, W2, b2, W3, b3, feats, 7, 0);
  pinv_kernel<<<dim3(BATCH), 256, 0, stream>>>(feats, dt, pinvb);

  for (int it = 0; it < 5; ++it) {
    encode_kernel<<<dim3(NPTS/PT, 1, BATCH), ETH, 0, stream>>>(
        p_src, mean_src, W1effL, b1effL, W2, b2, W3, b3, f1, 1, 1);
    update_kernel<<<dim3(BATCH), 256, 0, stream>>>(
        feats, f1, pinvb, g_buf, W1, b1, W1effL, b1effL, f1, r_out,
        mean_tgt, mean_src, est_g, (it == 4) ? 1 : 0);
  }
  loss_kernel<<<dim3(NPTS/256, BATCH), 256, 0, stream>>>(p_src, est_g, igt_inv, loss_out);
}

// Round 5
// 707.761 us; speedup vs baseline: 1.1513x; 1.1513x over previous
//
#include <hip/hip_runtime.h>
#include <math.h>

#define BATCH 8
#define NPTS 2048
#define KF 1024
#define PTB 256   // points per encode block (4 waves x 64)

typedef short s16x8 __attribute__((ext_vector_type(8)));
typedef float f32x4 __attribute__((ext_vector_type(4)));

// All operand layouts of 16x16x32 bf16 are HW-verified (m89/m91/m97/m120):
//  A: lane holds A[m=lane&15][k=(lane>>4)*8+j]
//  B: lane holds B[k=(lane>>4)*8+j][n=lane&15]
//  C/D: lane,reg holds C[row=(lane>>4)*4+reg][col=lane&15]
#define MFMA(a,b,c) __builtin_amdgcn_mfma_f32_16x16x32_bf16((a),(b),(c),0,0,0)

// ---------------- bf16 3-way split (hi/mid/lo): x = h+m+l to 2^-24 rel ----------------
__device__ __forceinline__ unsigned short f32_to_bf16_rn(float x) {
  unsigned int u = __float_as_uint(x);
  unsigned int r = (u + 0x7fffu + ((u >> 16) & 1u)) >> 16;
  return (unsigned short)r;
}
__device__ __forceinline__ float bf16_bits_to_f32(unsigned short h) {
  return __uint_as_float(((unsigned int)h) << 16);
}
__device__ __forceinline__ void split3_bf16(float x, short& h, short& m, short& l) {
  unsigned short hb = f32_to_bf16_rn(x);
  float fh = bf16_bits_to_f32(hb);
  float r1 = x - fh;
  unsigned short mb = f32_to_bf16_rn(r1);
  float fm = bf16_bits_to_f32(mb);
  unsigned short lb = f32_to_bf16_rn(r1 - fm);
  h = (short)hb; m = (short)mb; l = (short)lb;
}

// ---------------- misc device helpers ----------------
__device__ __forceinline__ void mat3mul(const float* A, const float* Bm, float* C) {
#pragma unroll
  for (int i = 0; i < 3; ++i)
#pragma unroll
    for (int j = 0; j < 3; ++j)
      C[i*3+j] = A[i*3+0]*Bm[0*3+j] + A[i*3+1]*Bm[1*3+j] + A[i*3+2]*Bm[2*3+j];
}

__device__ void se3_exp_dev(const float* x, float* R, float* p) {
  float wx = x[0], wy = x[1], wz = x[2];
  float vx = x[3], vy = x[4], vz = x[5];
  float t2 = wx*wx + wy*wy + wz*wz;
  float t = sqrtf(t2);
  float A, Bc, Cc;
  if (t < 1e-6f) {
    A  = 1.f - t2*(1.f/6.f);
    Bc = 0.5f - t2*(1.f/24.f);
    Cc = (1.f/6.f) - t2*(1.f/120.f);
  } else {
    float s = sinf(t), c = cosf(t);
    A  = s / t;
    Bc = (1.f - c) / t2;
    Cc = (t - s) / (t2 * t);
  }
  float W[9]  = {0.f, -wz, wy,  wz, 0.f, -wx,  -wy, wx, 0.f};
  float W2[9];
  mat3mul(W, W, W2);
#pragma unroll
  for (int i = 0; i < 9; ++i) {
    float I = (i == 0 || i == 4 || i == 8) ? 1.f : 0.f;
    R[i] = I + A*W[i] + Bc*W2[i];
  }
  float V[9];
#pragma unroll
  for (int i = 0; i < 9; ++i) {
    float I = (i == 0 || i == 4 || i == 8) ? 1.f : 0.f;
    V[i] = I + Bc*W[i] + Cc*W2[i];
  }
  p[0] = V[0]*vx + V[1]*vy + V[2]*vz;
  p[1] = V[3]*vx + V[4]*vy + V[5]*vz;
  p[2] = V[6]*vx + V[7]*vy + V[8]*vz;
}

__device__ __forceinline__ void atomicMaxFloat(float* addr, float val) {
  if (__float_as_uint(val) >> 31) {
    atomicMin((unsigned int*)addr, __float_as_uint(val));
  } else {
    atomicMax((int*)addr, __float_as_int(val));
  }
}

// ---------------- small kernels (R0-verified) ----------------
__global__ void means_kernel(const float* __restrict__ tgt, const float* __restrict__ src,
                             float* __restrict__ mean_tgt, float* __restrict__ mean_src) {
  int which = blockIdx.x & 1, b = blockIdx.x >> 1;
  const float* p = (which ? src : tgt) + (size_t)b*NPTS*3;
  float* m = (which ? mean_src : mean_tgt) + b*3;
  int t = threadIdx.x;
  float s0 = 0.f, s1 = 0.f, s2 = 0.f;
  for (int i = t; i < NPTS; i += 256) {
    s0 += p[i*3+0]; s1 += p[i*3+1]; s2 += p[i*3+2];
  }
  __shared__ float red[256][3];
  red[t][0] = s0; red[t][1] = s1; red[t][2] = s2;
  __syncthreads();
  for (int s = 128; s > 0; s >>= 1) {
    if (t < s) { red[t][0] += red[t+s][0]; red[t][1] += red[t+s][1]; red[t][2] += red[t+s][2]; }
    __syncthreads();
  }
  if (t == 0) {
    m[0] = red[0][0] * (1.f/NPTS);
    m[1] = red[0][1] * (1.f/NPTS);
    m[2] = red[0][2] * (1.f/NPTS);
  }
}

__global__ void setup_kernel(const float* __restrict__ dt, const float* __restrict__ W1,
                             const float* __restrict__ b1, const float* __restrict__ igt_twist,
                             float* __restrict__ feats, float* __restrict__ f1,
                             float* __restrict__ W1eff7, float* __restrict__ b1eff7,
                             float* __restrict__ W1effL, float* __restrict__ b1effL,
                             float* __restrict__ g_buf, float* __restrict__ igt_inv,
                             float* __restrict__ loss_out) {
  int t = threadIdx.x;
  for (int i = t; i < BATCH*7*KF; i += 256) feats[i] = -INFINITY;
  for (int i = t; i < BATCH*KF;   i += 256) f1[i]    = -INFINITY;
  for (int i = t; i < BATCH*192;  i += 256) W1effL[i] = W1[i % 192];
  for (int i = t; i < BATCH*64;   i += 256) b1effL[i] = b1[i & 63];
  if (t < 192) W1eff7[t] = W1[t];
  if (t < 64)  b1eff7[t] = b1[t];
  if (t < BATCH*16) {
    int i = t & 15;
    g_buf[t] = (i == 0 || i == 5 || i == 10 || i == 15) ? 1.f : 0.f;
  }
  if (t == 0) *loss_out = 0.f;
  if (t < 6) {
    float tw[6] = {0.f,0.f,0.f,0.f,0.f,0.f};
    tw[t] = -dt[t];
    float R[9], tr[3];
    se3_exp_dev(tw, R, tr);
    float* Wd = W1eff7 + (t+1)*192;
    for (int d = 0; d < 3; ++d)
      for (int c = 0; c < 64; ++c)
        Wd[d*64+c] = R[0*3+d]*W1[c] + R[1*3+d]*W1[64+c] + R[2*3+d]*W1[128+c];
    float* bd = b1eff7 + (t+1)*64;
    for (int c = 0; c < 64; ++c)
      bd[c] = b1[c] + tr[0]*W1[c] + tr[1]*W1[64+c] + tr[2]*W1[128+c];
  }
  if (t >= 32 && t < 32+BATCH) {
    int b = t - 32;
    float R[9], tr[3];
    se3_exp_dev(igt_twist + b*6, R, tr);
    float* inv = igt_inv + b*12;
    for (int r = 0; r < 3; ++r) {
      inv[r*4+0] = R[0*3+r];
      inv[r*4+1] = R[1*3+r];
      inv[r*4+2] = R[2*3+r];
      inv[r*4+3] = -(R[0*3+r]*tr[0] + R[1*3+r]*tr[1] + R[2*3+r]*tr[2]);
    }
  }
}

// ---------------- weight packs: 16x16x32 B-fragment order, 3-level bf16 split ----------------
// B element (k, n) -> lane = ((k&31)>>3)*16 + (n&15), j = k&7; tile (nt = n>>4, ks = k>>5)
__global__ void pack_w3_kernel(const float* __restrict__ W3, short* __restrict__ H,
                               short* __restrict__ M, short* __restrict__ L) {
  int i = blockIdx.x*256 + threadIdx.x;   // 128*1024
  int k = i >> 10, n = i & 1023;
  short h, m, l;
  split3_bf16(W3[i], h, m, l);
  int nt = n >> 4, col = n & 15;
  int ks3 = k >> 5, rr = k & 31;
  int lane = (rr >> 3)*16 + col, jj = rr & 7;
  int dst = ((nt*4 + ks3)*64 + lane)*8 + jj;
  H[dst] = h; M[dst] = m; L[dst] = l;
}

__global__ void pack_w2_kernel(const float* __restrict__ W2, short* __restrict__ H,
                               short* __restrict__ M, short* __restrict__ L) {
  int i = blockIdx.x*256 + threadIdx.x;   // 64*128
  int k = i >> 7, n = i & 127;
  short h, m, l;
  split3_bf16(W2[i], h, m, l);
  int nt2 = n >> 4, col = n & 15;
  int ks = k >> 5, rr = k & 31;
  int lane = (rr >> 3)*16 + col, jj = rr & 7;
  int dst = ((nt2*2 + ks)*64 + lane)*8 + jj;
  H[dst] = h; M[dst] = m; L[dst] = l;
}

// ---------------- MFMA encode ----------------
__device__ __forceinline__ f32x4 zero4() {
  f32x4 z; z[0]=0.f; z[1]=0.f; z[2]=0.f; z[3]=0.f; return z;
}

__device__ __forceinline__ void loadB3(s16x8 B[3][4],
    const short* __restrict__ W3h, const short* __restrict__ W3m,
    const short* __restrict__ W3l, int nt, int l) {
#pragma unroll
  for (int ks = 0; ks < 4; ++ks) {
    int off = ((nt*4 + ks)*64 + l)*8;
    B[0][ks] = *(const s16x8*)(W3h + off);
    B[1][ks] = *(const s16x8*)(W3m + off);
    B[2][ks] = *(const s16x8*)(W3l + off);
  }
}

__device__ __forceinline__ void l3_body(
    const s16x8 (&Ah)[4][4], const s16x8 (&Am)[4][4], const s16x8 (&Al)[4][4],
    const s16x8 (&B)[3][4],
    int nt, int l, const float* __restrict__ b3, float* __restrict__ outp) {
  f32x4 a[4] = {zero4(), zero4(), zero4(), zero4()};
#pragma unroll
  for (int ks = 0; ks < 4; ++ks) {
#pragma unroll
    for (int p = 0; p < 4; ++p) a[p] = MFMA(Ah[p][ks], B[2][ks], a[p]);  // h*l
#pragma unroll
    for (int p = 0; p < 4; ++p) a[p] = MFMA(Al[p][ks], B[0][ks], a[p]);  // l*h
#pragma unroll
    for (int p = 0; p < 4; ++p) a[p] = MFMA(Am[p][ks], B[1][ks], a[p]);  // m*m
#pragma unroll
    for (int p = 0; p < 4; ++p) a[p] = MFMA(Ah[p][ks], B[1][ks], a[p]);  // h*m
#pragma unroll
    for (int p = 0; p < 4; ++p) a[p] = MFMA(Am[p][ks], B[0][ks], a[p]);  // m*h
#pragma unroll
    for (int p = 0; p < 4; ++p) a[p] = MFMA(Ah[p][ks], B[0][ks], a[p]);  // h*h
  }
  float mx = -INFINITY;
#pragma unroll
  for (int p = 0; p < 4; ++p)
#pragma unroll
    for (int r = 0; r < 4; ++r) mx = fmaxf(mx, a[p][r]);
  mx = fmaxf(mx, __shfl_xor(mx, 16, 64));
  mx = fmaxf(mx, __shfl_xor(mx, 32, 64));
  if (l < 16) {
    int feat = nt*16 + l;
    atomicMaxFloat(outp + feat, mx + b3[feat]);
  }
}

// grid: (NPTS/PTB, NJ*FG, BATCH), 256 threads = 4 waves x 64 points (4 ptiles of 16).
__global__ __launch_bounds__(256, 1) void encode_mfma(
    const float* __restrict__ pts, const float* __restrict__ mean,
    const float* __restrict__ W1e, const float* __restrict__ b1e,
    const short* __restrict__ W2h, const short* __restrict__ W2m, const short* __restrict__ W2l,
    const short* __restrict__ W3h, const short* __restrict__ W3m, const short* __restrict__ W3l,
    const float* __restrict__ b2, const float* __restrict__ b3,
    float* __restrict__ out, int NJ, int FG, int per_batch) {
  const int t = threadIdx.x;
  const int w = t >> 6, l = t & 63;
  const int lm = l & 15, q = l >> 4;
  const int pblk = blockIdx.x;
  const int j = blockIdx.y / FG, fg = blockIdx.y % FG;
  const int b = blockIdx.z;
  const int widx = per_batch ? b : j;
  const int NT_PER = 64 / FG;
  const int nt0 = fg * NT_PER;

  // per-wave LDS scratch: h2 C-layout -> layer-3 A-layout (same-wave DS ordering, no barriers)
  __shared__ short scr[4][3][2048];   // 48 KB total

  // ---- the wave's 64 centered points: ptile p, row lm ----
  const int ptbase = pblk*PTB + w*64;
  float mx0 = mean[b*3+0], my0 = mean[b*3+1], mz0 = mean[b*3+2];
  float px[4], py[4], pz[4];
#pragma unroll
  for (int p = 0; p < 4; ++p) {
    const float* pp = pts + ((size_t)b*NPTS + ptbase + p*16 + lm)*3;
    px[p] = pp[0] - mx0; py[p] = pp[1] - my0; pz[p] = pp[2] - mz0;
  }

  const float* w1 = W1e + widx*192;
  const float* bb1 = b1e + widx*64;

  s16x8 A3h[4][4], A3m[4][4], A3l[4][4];

#pragma unroll
  for (int p = 0; p < 4; ++p) {
    // ---- layer 1: A2 fragments (this ptile). lane: point lm, channels ks*32 + q*8 + jj ----
    s16x8 A2h[2], A2m[2], A2l[2];
#pragma unroll
    for (int ks = 0; ks < 2; ++ks) {
      const int c0 = ks*32 + q*8;
      float wa[8], wb[8], wc[8], bv[8];
      *(float4*)&wa[0] = *(const float4*)(w1 + c0);
      *(float4*)&wa[4] = *(const float4*)(w1 + c0 + 4);
      *(float4*)&wb[0] = *(const float4*)(w1 + 64 + c0);
      *(float4*)&wb[4] = *(const float4*)(w1 + 64 + c0 + 4);
      *(float4*)&wc[0] = *(const float4*)(w1 + 128 + c0);
      *(float4*)&wc[4] = *(const float4*)(w1 + 128 + c0 + 4);
      *(float4*)&bv[0] = *(const float4*)(bb1 + c0);
      *(float4*)&bv[4] = *(const float4*)(bb1 + c0 + 4);
#pragma unroll
      for (int jj = 0; jj < 8; ++jj) {
        float h = fmaf(px[p], wa[jj], fmaf(py[p], wb[jj], fmaf(pz[p], wc[jj], bv[jj])));
        h = fmaxf(h, 0.f);
        short sh, sm, sl;
        split3_bf16(h, sh, sm, sl);
        A2h[ks][jj] = sh; A2m[ks][jj] = sm; A2l[ks][jj] = sl;
      }
    }
    // ---- layer 2: 8 ntiles of 16 features; 6-product accumulate; relayout via scratch ----
#pragma unroll
    for (int nt2 = 0; nt2 < 8; ++nt2) {
      f32x4 acc = zero4();
#pragma unroll
      for (int ks = 0; ks < 2; ++ks) {
        const int base = ((nt2*2 + ks)*64 + l)*8;
        const s16x8 Bh = *(const s16x8*)(W2h + base);
        const s16x8 Bm = *(const s16x8*)(W2m + base);
        const s16x8 Bl = *(const s16x8*)(W2l + base);
        acc = MFMA(A2h[ks], Bl, acc);
        acc = MFMA(A2l[ks], Bh, acc);
        acc = MFMA(A2m[ks], Bm, acc);
        acc = MFMA(A2h[ks], Bm, acc);
        acc = MFMA(A2m[ks], Bh, acc);
        acc = MFMA(A2h[ks], Bh, acc);
      }
      // C: row = q*4 + r (point), col = lm -> feature c2 = nt2*16 + lm
      const int c2 = nt2*16 + lm;
      const float b2v = b2[c2];
      const int ks3 = c2 >> 5;
      const int k31 = c2 & 31;
      const int qw = k31 >> 3, jw = k31 & 7;
#pragma unroll
      for (int r = 0; r < 4; ++r) {
        const int mrow = q*4 + r;
        float h = fmaxf(acc[r] + b2v, 0.f);
        short sh, sm, sl;
        split3_bf16(h, sh, sm, sl);
        const int idx = (ks3*64 + qw*16 + mrow)*8 + jw;
        scr[w][0][idx] = sh;
        scr[w][1][idx] = sm;
        scr[w][2][idx] = sl;
      }
    }
    // read back this ptile's layer-3 A-fragments
#pragma unroll
    for (int ks3 = 0; ks3 < 4; ++ks3) {
      const int base = (ks3*64 + l)*8;
      A3h[p][ks3] = *(const s16x8*)&scr[w][0][base];
      A3m[p][ks3] = *(const s16x8*)&scr[w][1][base];
      A3l[p][ks3] = *(const s16x8*)&scr[w][2][base];
    }
  }

  // ---- layer 3: nt-loop with B register ping-pong ----
  float* outp = out + ((size_t)b*NJ + j)*KF;
  s16x8 B0[3][4], B1[3][4];
  loadB3(B0, W3h, W3m, W3l, nt0, l);
  for (int k = 0; k < NT_PER; k += 2) {
    loadB3(B1, W3h, W3m, W3l, nt0 + k + 1, l);
    l3_body(A3h, A3m, A3l, B0, nt0 + k, l, b3, outp);
    if (k + 2 < NT_PER) loadB3(B0, W3h, W3m, W3l, nt0 + k + 2, l);
    l3_body(A3h, A3m, A3l, B1, nt0 + k + 1, l, b3, outp);
  }
}

// ---------------- pinv / update / loss (R0-verified) ----------------
__global__ void pinv_kernel(const float* __restrict__ feats, const float* __restrict__ dt,
                            float* __restrict__ pinv) {
  int b = blockIdx.x, t = threadIdx.x;
  const float* f0 = feats + (size_t)b*7*KF;
  const float* fj = f0 + KF;
  float idt[6];
#pragma unroll
  for (int i = 0; i < 6; ++i) idt[i] = 1.f / dt[i];
  float H[21];
#pragma unroll
  for (int i = 0; i < 21; ++i) H[i] = 0.f;
  for (int k = t; k < KF; k += 256) {
    float f0k = f0[k];
    float Jk[6];
#pragma unroll
    for (int i = 0; i < 6; ++i) Jk[i] = (f0k - fj[i*KF + k]) * idt[i];
    int idx = 0;
#pragma unroll
    for (int i = 0; i < 6; ++i)
#pragma unroll
      for (int jj = i; jj < 6; ++jj) H[idx++] += Jk[i]*Jk[jj];
  }
  __shared__ float red[256*21];
#pragma unroll
  for (int i = 0; i < 21; ++i) red[t*21+i] = H[i];
  __syncthreads();
  for (int s = 128; s > 0; s >>= 1) {
    if (t < s)
      for (int i = 0; i < 21; ++i) red[t*21+i] += red[(t+s)*21+i];
    __syncthreads();
  }
  __shared__ float s_hinv[36];
  if (t == 0) {
    double A[6][12];
    int idx = 0;
    for (int i = 0; i < 6; ++i)
      for (int jj = i; jj < 6; ++jj) { A[i][jj] = red[idx]; A[jj][i] = red[idx]; idx++; }
    for (int i = 0; i < 6; ++i)
      for (int jj = 0; jj < 6; ++jj) A[i][6+jj] = (i == jj) ? 1.0 : 0.0;
    for (int col = 0; col < 6; ++col) {
      int piv = col; double best = fabs(A[col][col]);
      for (int r2 = col+1; r2 < 6; ++r2) {
        double v = fabs(A[r2][col]);
        if (v > best) { best = v; piv = r2; }
      }
      if (piv != col)
        for (int jj = 0; jj < 12; ++jj) { double tmp = A[col][jj]; A[col][jj] = A[piv][jj]; A[piv][jj] = tmp; }
      double inv = 1.0 / A[col][col];
      for (int jj = 0; jj < 12; ++jj) A[col][jj] *= inv;
      for (int r2 = 0; r2 < 6; ++r2) if (r2 != col) {
        double f = A[r2][col];
        for (int jj = 0; jj < 12; ++jj) A[r2][jj] -= f * A[col][jj];
      }
    }
    for (int i = 0; i < 6; ++i)
      for (int jj = 0; jj < 6; ++jj) s_hinv[i*6+jj] = (float)A[i][6+jj];
  }
  __syncthreads();
  for (int k = t; k < KF; k += 256) {
    float f0k = f0[k];
    float Jk[6];
#pragma unroll
    for (int i = 0; i < 6; ++i) Jk[i] = (f0k - fj[i*KF + k]) * idt[i];
#pragma unroll
    for (int i = 0; i < 6; ++i) {
      float s = 0.f;
#pragma unroll
      for (int jj = 0; jj < 6; ++jj) s += s_hinv[i*6+jj] * Jk[jj];
      pinv[((size_t)b*6 + i)*KF + k] = s;
    }
  }
}

__global__ void update_kernel(const float* __restrict__ feats, const float* __restrict__ f1,
                              const float* __restrict__ pinv, float* __restrict__ g_buf,
                              const float* __restrict__ W1, const float* __restrict__ b1,
                              float* __restrict__ W1effL, float* __restrict__ b1effL,
                              float* __restrict__ f1r, float* __restrict__ r_out,
                              const float* __restrict__ mean_tgt, const float* __restrict__ mean_src,
                              float* __restrict__ est_g, int final_it) {
  int b = blockIdx.x, t = threadIdx.x;
  const float* f0  = feats + (size_t)b*7*KF;
  const float* f1b = f1 + (size_t)b*KF;
  float acc[6] = {0.f,0.f,0.f,0.f,0.f,0.f};
  for (int k = t; k < KF; k += 256) {
    float r = f1b[k] - f0[k];
    r_out[(size_t)b*KF + k] = r;
#pragma unroll
    for (int i = 0; i < 6; ++i) acc[i] += pinv[((size_t)b*6+i)*KF + k] * r;
  }
  __shared__ float red[256*6];
#pragma unroll
  for (int i = 0; i < 6; ++i) red[t*6+i] = acc[i];
  __syncthreads();
  for (int s = 128; s > 0; s >>= 1) {
    if (t < s)
      for (int i = 0; i < 6; ++i) red[t*6+i] += red[(t+s)*6+i];
    __syncthreads();
  }
  __shared__ float s_g[16];
  if (t == 0) {
    float dx[6];
#pragma unroll
    for (int i = 0; i < 6; ++i) dx[i] = -red[i];
    float R[9], p[3];
    se3_exp_dev(dx, R, p);
    float* g = g_buf + b*16;
    float gn[16];
    for (int r2 = 0; r2 < 3; ++r2)
      for (int c = 0; c < 4; ++c)
        gn[r2*4+c] = R[r2*3+0]*g[c] + R[r2*3+1]*g[4+c] + R[r2*3+2]*g[8+c] + p[r2]*g[12+c];
    gn[12] = 0.f; gn[13] = 0.f; gn[14] = 0.f; gn[15] = 1.f;
    for (int i = 0; i < 16; ++i) { g[i] = gn[i]; s_g[i] = gn[i]; }
    if (final_it) {
      const float* p0m = mean_tgt + b*3;
      const float* p1m = mean_src + b*3;
      float* e = est_g + b*12;
      for (int r2 = 0; r2 < 3; ++r2) {
        e[r2*4+0] = gn[r2*4+0];
        e[r2*4+1] = gn[r2*4+1];
        e[r2*4+2] = gn[r2*4+2];
        e[r2*4+3] = gn[r2*4+3]
                  - (gn[r2*4+0]*p1m[0] + gn[r2*4+1]*p1m[1] + gn[r2*4+2]*p1m[2])
                  + p0m[r2];
      }
    }
  }
  __syncthreads();
  if (!final_it) {
    for (int i = t; i < 192; i += 256) {
      int d = i >> 6, c = i & 63;
      W1effL[b*192 + i] = s_g[0*4+d]*W1[c] + s_g[1*4+d]*W1[64+c] + s_g[2*4+d]*W1[128+c];
    }
    for (int i = t; i < 64; i += 256)
      b1effL[b*64 + i] = b1[i] + s_g[3]*W1[i] + s_g[7]*W1[64+i] + s_g[11]*W1[128+i];
    for (int k = t; k < KF; k += 256) f1r[(size_t)b*KF + k] = -INFINITY;
  }
}

__global__ void loss_kernel(const float* __restrict__ p_src, const float* __restrict__ est_g,
                            const float* __restrict__ igt_inv, float* __restrict__ loss_out) {
  int b = blockIdx.y, tile = blockIdx.x, t = threadIdx.x;
  int n = tile*256 + t;
  const float* e = est_g + b*12;
  const float* v = igt_inv + b*12;
  const float* p = p_src + ((size_t)b*NPTS + n)*3;
  float px = p[0], py = p[1], pz = p[2];
  float s = 0.f;
#pragma unroll
  for (int r2 = 0; r2 < 3; ++r2) {
    float d1 = e[r2*4+0]*px + e[r2*4+1]*py + e[r2*4+2]*pz + e[r2*4+3];
    float d2 = v[r2*4+0]*px + v[r2*4+1]*py + v[r2*4+2]*pz + v[r2*4+3];
    s += fabsf(d1 - d2);
  }
  __shared__ float red[256];
  red[t] = s;
  __syncthreads();
  for (int st = 128; st > 0; st >>= 1) {
    if (t < st) red[t] += red[t+st];
    __syncthreads();
  }
  if (t == 0) atomicAdd(loss_out, red[0] * (1.f/((float)BATCH*NPTS*3)));
}

// ---------------- launcher ----------------
extern "C" void kernel_launch(void* const* d_in, const int* in_sizes, int n_in,
                              void* d_out, int out_size, void* d_ws, size_t ws_size,
                              hipStream_t stream) {
  const float* p_src     = (const float*)d_in[0];
  const float* p_tgt     = (const float*)d_in[1];
  const float* igt_twist = (const float*)d_in[2];
  const float* dt        = (const float*)d_in[3];
  const float* W1        = (const float*)d_in[4];
  const float* b1        = (const float*)d_in[5];
  const float* W2        = (const float*)d_in[6];
  const float* b2        = (const float*)d_in[7];
  const float* W3        = (const float*)d_in[8];
  const float* b3        = (const float*)d_in[9];
  float* out = (float*)d_out;

  // FIX (R4): mean_* need BATCH*3=24 floats, igt_inv/est_g need BATCH*12=96 floats.
  // R1-R3 reserved 16/16/24/24 -> aliasing corrupted means (and igt_inv at final
  // iter), the shared ~0.156 absmax across three different encode implementations.
  float* ws = (float*)d_ws;
  float* mean_tgt = ws;  ws += 32;   // 24 used, padded for alignment
  float* mean_src = ws;  ws += 32;   // 24 used
  float* W1eff7   = ws;  ws += 7*192;
  float* b1eff7   = ws;  ws += 7*64;
  float* feats    = ws;  ws += BATCH*7*KF;
  float* W1effL   = ws;  ws += BATCH*192;
  float* b1effL   = ws;  ws += BATCH*64;
  float* f1       = ws;  ws += BATCH*KF;
  float* g_buf    = ws;  ws += BATCH*16;
  float* pinvb    = ws;  ws += BATCH*6*KF;
  float* igt_inv  = ws;  ws += 96;   // BATCH*12
  float* est_g    = ws;  ws += 96;   // BATCH*12
  short* W2h = (short*)ws;  ws += 8192/2;
  short* W2m = (short*)ws;  ws += 8192/2;
  short* W2l = (short*)ws;  ws += 8192/2;
  short* W3h = (short*)ws;  ws += 131072/2;
  short* W3m = (short*)ws;  ws += 131072/2;
  short* W3l = (short*)ws;  ws += 131072/2;

  float* r_out    = out;
  float* loss_out = out + BATCH*KF;

  means_kernel<<<dim3(BATCH*2), 256, 0, stream>>>(p_tgt, p_src, mean_tgt, mean_src);
  setup_kernel<<<1, 256, 0, stream>>>(dt, W1, b1, igt_twist, feats, f1, W1eff7, b1eff7,
                                      W1effL, b1effL, g_buf, igt_inv, loss_out);
  pack_w2_kernel<<<dim3(8192/256), 256, 0, stream>>>(W2, W2h, W2m, W2l);
  pack_w3_kernel<<<dim3(131072/256), 256, 0, stream>>>(W3, W3h, W3m, W3l);

  // f0 + 6 twist-perturbed encodes: FG=1, NJ=7 -> grid (8,7,8), NT_PER=64
  encode_mfma<<<dim3(NPTS/PTB, 7, BATCH), 256, 0, stream>>>(
      p_tgt, mean_tgt, W1eff7, b1eff7, W2h, W2m, W2l, W3h, W3m, W3l, b2, b3, feats, 7, 1, 0);
  pinv_kernel<<<dim3(BATCH), 256, 0, stream>>>(feats, dt, pinvb);

  for (int it = 0; it < 5; ++it) {
    // loop encode: FG=8 -> grid (8,8,8), NT_PER=8
    encode_mfma<<<dim3(NPTS/PTB, 8, BATCH), 256, 0, stream>>>(
        p_src, mean_src, W1effL, b1effL, W2h, W2m, W2l, W3h, W3m, W3l, b2, b3, f1, 1, 8, 1);
    update_kernel<<<dim3(BATCH), 256, 0, stream>>>(
        feats, f1, pinvb, g_buf, W1, b1, W1effL, b1effL, f1, r_out,
        mean_tgt, mean_src, est_g, (it == 4) ? 1 : 0);
  }
  loss_kernel<<<dim3(NPTS/256, BATCH), 256, 0, stream>>>(p_src, est_g, igt_inv, loss_out);
}

// Round 6
// 460.175 us; speedup vs baseline: 1.7707x; 1.5380x over previous
//
#include <hip/hip_runtime.h>
#include <math.h>

#define BATCH 8
#define NPTS 2048
#define KF 1024
#define PTW 32    // points per wave (2 ptiles of 16); 1 wave per block

typedef _Float16 f16x8 __attribute__((ext_vector_type(8)));
typedef float f32x4 __attribute__((ext_vector_type(4)));

// 16x16x32 layouts HW-verified (m89/m91/m97/m120); dtype-independent:
//  A: lane holds A[m=lane&15][k=(lane>>4)*8+j]
//  B: lane holds B[k=(lane>>4)*8+j][n=lane&15]
//  C/D: lane,reg holds C[row=(lane>>4)*4+reg][col=lane&15]
#define MFMA16(a,b,c) __builtin_amdgcn_mfma_f32_16x16x32_f16((a),(b),(c),0,0,0)

#define FSCALE 256.0f
#define INV16  (1.0f/65536.0f)

// fp16 2-way split of (x*256): hi+lo represents xs to ~2^-22 relative; all 4
// cross products kept -> f32-equivalent GEMM precision after GN amplification.
__device__ __forceinline__ void split_f16s(float x, _Float16& hi, _Float16& lo) {
  float xs = x * FSCALE;
  hi = (_Float16)xs;
  lo = (_Float16)(xs - (float)hi);
}

// ---------------- misc device helpers ----------------
__device__ __forceinline__ void mat3mul(const float* A, const float* Bm, float* C) {
#pragma unroll
  for (int i = 0; i < 3; ++i)
#pragma unroll
    for (int j = 0; j < 3; ++j)
      C[i*3+j] = A[i*3+0]*Bm[0*3+j] + A[i*3+1]*Bm[1*3+j] + A[i*3+2]*Bm[2*3+j];
}

__device__ void se3_exp_dev(const float* x, float* R, float* p) {
  float wx = x[0], wy = x[1], wz = x[2];
  float vx = x[3], vy = x[4], vz = x[5];
  float t2 = wx*wx + wy*wy + wz*wz;
  float t = sqrtf(t2);
  float A, Bc, Cc;
  if (t < 1e-6f) {
    A  = 1.f - t2*(1.f/6.f);
    Bc = 0.5f - t2*(1.f/24.f);
    Cc = (1.f/6.f) - t2*(1.f/120.f);
  } else {
    float s = sinf(t), c = cosf(t);
    A  = s / t;
    Bc = (1.f - c) / t2;
    Cc = (t - s) / (t2 * t);
  }
  float W[9]  = {0.f, -wz, wy,  wz, 0.f, -wx,  -wy, wx, 0.f};
  float W2[9];
  mat3mul(W, W, W2);
#pragma unroll
  for (int i = 0; i < 9; ++i) {
    float I = (i == 0 || i == 4 || i == 8) ? 1.f : 0.f;
    R[i] = I + A*W[i] + Bc*W2[i];
  }
  float V[9];
#pragma unroll
  for (int i = 0; i < 9; ++i) {
    float I = (i == 0 || i == 4 || i == 8) ? 1.f : 0.f;
    V[i] = I + Bc*W[i] + Cc*W2[i];
  }
  p[0] = V[0]*vx + V[1]*vy + V[2]*vz;
  p[1] = V[3]*vx + V[4]*vy + V[5]*vz;
  p[2] = V[6]*vx + V[7]*vy + V[8]*vz;
}

__device__ __forceinline__ void atomicMaxFloat(float* addr, float val) {
  if (__float_as_uint(val) >> 31) {
    atomicMin((unsigned int*)addr, __float_as_uint(val));
  } else {
    atomicMax((int*)addr, __float_as_int(val));
  }
}

// ---------------- small kernels (verified) ----------------
__global__ void means_kernel(const float* __restrict__ tgt, const float* __restrict__ src,
                             float* __restrict__ mean_tgt, float* __restrict__ mean_src) {
  int which = blockIdx.x & 1, b = blockIdx.x >> 1;
  const float* p = (which ? src : tgt) + (size_t)b*NPTS*3;
  float* m = (which ? mean_src : mean_tgt) + b*3;
  int t = threadIdx.x;
  float s0 = 0.f, s1 = 0.f, s2 = 0.f;
  for (int i = t; i < NPTS; i += 256) {
    s0 += p[i*3+0]; s1 += p[i*3+1]; s2 += p[i*3+2];
  }
  __shared__ float red[256][3];
  red[t][0] = s0; red[t][1] = s1; red[t][2] = s2;
  __syncthreads();
  for (int s = 128; s > 0; s >>= 1) {
    if (t < s) { red[t][0] += red[t+s][0]; red[t][1] += red[t+s][1]; red[t][2] += red[t+s][2]; }
    __syncthreads();
  }
  if (t == 0) {
    m[0] = red[0][0] * (1.f/NPTS);
    m[1] = red[0][1] * (1.f/NPTS);
    m[2] = red[0][2] * (1.f/NPTS);
  }
}

__global__ void setup_kernel(const float* __restrict__ dt, const float* __restrict__ W1,
                             const float* __restrict__ b1, const float* __restrict__ igt_twist,
                             float* __restrict__ feats, float* __restrict__ f1,
                             float* __restrict__ W1eff7, float* __restrict__ b1eff7,
                             float* __restrict__ W1effL, float* __restrict__ b1effL,
                             float* __restrict__ g_buf, float* __restrict__ igt_inv,
                             float* __restrict__ loss_out) {
  int t = threadIdx.x;
  for (int i = t; i < BATCH*7*KF; i += 256) feats[i] = -INFINITY;
  for (int i = t; i < BATCH*KF;   i += 256) f1[i]    = -INFINITY;
  for (int i = t; i < BATCH*192;  i += 256) W1effL[i] = W1[i % 192];
  for (int i = t; i < BATCH*64;   i += 256) b1effL[i] = b1[i & 63];
  if (t < 192) W1eff7[t] = W1[t];
  if (t < 64)  b1eff7[t] = b1[t];
  if (t < BATCH*16) {
    int i = t & 15;
    g_buf[t] = (i == 0 || i == 5 || i == 10 || i == 15) ? 1.f : 0.f;
  }
  if (t == 0) *loss_out = 0.f;
  if (t < 6) {
    float tw[6] = {0.f,0.f,0.f,0.f,0.f,0.f};
    tw[t] = -dt[t];
    float R[9], tr[3];
    se3_exp_dev(tw, R, tr);
    float* Wd = W1eff7 + (t+1)*192;
    for (int d = 0; d < 3; ++d)
      for (int c = 0; c < 64; ++c)
        Wd[d*64+c] = R[0*3+d]*W1[c] + R[1*3+d]*W1[64+c] + R[2*3+d]*W1[128+c];
    float* bd = b1eff7 + (t+1)*64;
    for (int c = 0; c < 64; ++c)
      bd[c] = b1[c] + tr[0]*W1[c] + tr[1]*W1[64+c] + tr[2]*W1[128+c];
  }
  if (t >= 32 && t < 32+BATCH) {
    int b = t - 32;
    float R[9], tr[3];
    se3_exp_dev(igt_twist + b*6, R, tr);
    float* inv = igt_inv + b*12;
    for (int r = 0; r < 3; ++r) {
      inv[r*4+0] = R[0*3+r];
      inv[r*4+1] = R[1*3+r];
      inv[r*4+2] = R[2*3+r];
      inv[r*4+3] = -(R[0*3+r]*tr[0] + R[1*3+r]*tr[1] + R[2*3+r]*tr[2]);
    }
  }
}

// ---------------- weight packs: 16x16x32 B-fragment order, scaled fp16 hi/lo ----------------
// B element (k,n) -> lane = ((k&31)>>3)*16 + (n&15), j = k&7; tile (nt=n>>4, ks=k>>5)
__global__ void pack_w3_kernel(const float* __restrict__ W3,
                               _Float16* __restrict__ H, _Float16* __restrict__ L) {
  int i = blockIdx.x*256 + threadIdx.x;   // 128*1024
  int k = i >> 10, n = i & 1023;
  _Float16 hi, lo;
  split_f16s(W3[i], hi, lo);
  int nt = n >> 4, col = n & 15;
  int ks3 = k >> 5, rr = k & 31;
  int lane = (rr >> 3)*16 + col, jj = rr & 7;
  int dst = ((nt*4 + ks3)*64 + lane)*8 + jj;
  H[dst] = hi; L[dst] = lo;
}

__global__ void pack_w2_kernel(const float* __restrict__ W2,
                               _Float16* __restrict__ H, _Float16* __restrict__ L) {
  int i = blockIdx.x*256 + threadIdx.x;   // 64*128
  int k = i >> 7, n = i & 127;
  _Float16 hi, lo;
  split_f16s(W2[i], hi, lo);
  int nt2 = n >> 4, col = n & 15;
  int ks = k >> 5, rr = k & 31;
  int lane = (rr >> 3)*16 + col, jj = rr & 7;
  int dst = ((nt2*2 + ks)*64 + lane)*8 + jj;
  H[dst] = hi; L[dst] = lo;
}

// ---------------- MFMA encode ----------------
__device__ __forceinline__ f32x4 zero4() {
  f32x4 z; z[0]=0.f; z[1]=0.f; z[2]=0.f; z[3]=0.f; return z;
}

__device__ __forceinline__ void loadB3(f16x8 B[2][4],
    const _Float16* __restrict__ W3h, const _Float16* __restrict__ W3l,
    int nt, int l) {
#pragma unroll
  for (int ks = 0; ks < 4; ++ks) {
    int off = ((nt*4 + ks)*64 + l)*8;
    B[0][ks] = *(const f16x8*)(W3h + off);
    B[1][ks] = *(const f16x8*)(W3l + off);
  }
}

__device__ __forceinline__ void l3_body(
    const f16x8 (&Ah)[2][4], const f16x8 (&Al)[2][4],
    const f16x8 (&B)[2][4],
    int nt, int l, const float* __restrict__ b3, float* __restrict__ outp) {
  f32x4 a[2] = {zero4(), zero4()};
#pragma unroll
  for (int ks = 0; ks < 4; ++ks) {
#pragma unroll
    for (int p = 0; p < 2; ++p) a[p] = MFMA16(Al[p][ks], B[1][ks], a[p]);  // l*l
#pragma unroll
    for (int p = 0; p < 2; ++p) a[p] = MFMA16(Al[p][ks], B[0][ks], a[p]);  // l*h
#pragma unroll
    for (int p = 0; p < 2; ++p) a[p] = MFMA16(Ah[p][ks], B[1][ks], a[p]);  // h*l
#pragma unroll
    for (int p = 0; p < 2; ++p) a[p] = MFMA16(Ah[p][ks], B[0][ks], a[p]);  // h*h
  }
  float mx = -INFINITY;
#pragma unroll
  for (int p = 0; p < 2; ++p)
#pragma unroll
    for (int r = 0; r < 4; ++r) mx = fmaxf(mx, a[p][r]);
  mx = fmaxf(mx, __shfl_xor(mx, 16, 64));
  mx = fmaxf(mx, __shfl_xor(mx, 32, 64));
  if (l < 16) {
    int feat = nt*16 + l;
    atomicMaxFloat(outp + feat, mx*INV16 + b3[feat]);
  }
}

// grid: (NPTS/PTW, NJ*FG, BATCH); ONE wave (64 threads) per block, 32 points/wave.
// 1-wave blocks + 8KB LDS + capped VGPR -> 3 waves/SIMD target (vs R4's 9.5% occupancy).
__global__ __launch_bounds__(64, 3) void encode_mfma(
    const float* __restrict__ pts, const float* __restrict__ mean,
    const float* __restrict__ W1e, const float* __restrict__ b1e,
    const _Float16* __restrict__ W2h, const _Float16* __restrict__ W2l,
    const _Float16* __restrict__ W3h, const _Float16* __restrict__ W3l,
    const float* __restrict__ b2, const float* __restrict__ b3,
    float* __restrict__ out, int NJ, int FG, int per_batch) {
  const int l = threadIdx.x & 63;
  const int lm = l & 15, q = l >> 4;
  const int pblk = blockIdx.x;
  const int j = blockIdx.y / FG, fg = blockIdx.y % FG;
  const int b = blockIdx.z;
  const int widx = per_batch ? b : j;
  const int NT_PER = 64 / FG;
  const int nt0 = fg * NT_PER;

  // per-wave LDS scratch: h2 C-layout -> layer-3 A-layout (same-wave DS ordering)
  __shared__ _Float16 scr[2][2048];   // 8 KB

  // ---- the wave's 32 centered points: ptile p in {0,1}, row lm ----
  const int ptbase = pblk*PTW;
  float mx0 = mean[b*3+0], my0 = mean[b*3+1], mz0 = mean[b*3+2];
  float px[2], py[2], pz[2];
#pragma unroll
  for (int p = 0; p < 2; ++p) {
    const float* pp = pts + ((size_t)b*NPTS + ptbase + p*16 + lm)*3;
    px[p] = pp[0] - mx0; py[p] = pp[1] - my0; pz[p] = pp[2] - mz0;
  }

  const float* w1 = W1e + widx*192;
  const float* bb1 = b1e + widx*64;

  f16x8 A3h[2][4], A3l[2][4];

#pragma unroll
  for (int p = 0; p < 2; ++p) {
    // ---- layer 1: A2 fragments (this ptile); lane: point lm, channels ks*32 + q*8 + jj ----
    f16x8 A2h[2], A2l[2];
#pragma unroll
    for (int ks = 0; ks < 2; ++ks) {
      const int c0 = ks*32 + q*8;
      float wa[8], wb[8], wc[8], bv[8];
      *(float4*)&wa[0] = *(const float4*)(w1 + c0);
      *(float4*)&wa[4] = *(const float4*)(w1 + c0 + 4);
      *(float4*)&wb[0] = *(const float4*)(w1 + 64 + c0);
      *(float4*)&wb[4] = *(const float4*)(w1 + 64 + c0 + 4);
      *(float4*)&wc[0] = *(const float4*)(w1 + 128 + c0);
      *(float4*)&wc[4] = *(const float4*)(w1 + 128 + c0 + 4);
      *(float4*)&bv[0] = *(const float4*)(bb1 + c0);
      *(float4*)&bv[4] = *(const float4*)(bb1 + c0 + 4);
#pragma unroll
      for (int jj = 0; jj < 8; ++jj) {
        float h = fmaf(px[p], wa[jj], fmaf(py[p], wb[jj], fmaf(pz[p], wc[jj], bv[jj])));
        h = fmaxf(h, 0.f);
        _Float16 hi, lo;
        split_f16s(h, hi, lo);
        A2h[ks][jj] = hi; A2l[ks][jj] = lo;
      }
    }
    // ---- layer 2: 8 ntiles of 16 features; 4-product accumulate; relayout via scratch ----
#pragma unroll
    for (int nt2 = 0; nt2 < 8; ++nt2) {
      f32x4 acc = zero4();
#pragma unroll
      for (int ks = 0; ks < 2; ++ks) {
        const int base = ((nt2*2 + ks)*64 + l)*8;
        const f16x8 Bh = *(const f16x8*)(W2h + base);
        const f16x8 Bl = *(const f16x8*)(W2l + base);
        acc = MFMA16(A2l[ks], Bl, acc);
        acc = MFMA16(A2l[ks], Bh, acc);
        acc = MFMA16(A2h[ks], Bl, acc);
        acc = MFMA16(A2h[ks], Bh, acc);
      }
      // C: row = q*4 + r (point), col = lm -> feature c2 = nt2*16 + lm
      const int c2 = nt2*16 + lm;
      const float b2v = b2[c2];
      const int ks3 = c2 >> 5;
      const int k31 = c2 & 31;
      const int qw = k31 >> 3, jw = k31 & 7;
#pragma unroll
      for (int r = 0; r < 4; ++r) {
        const int mrow = q*4 + r;
        float h = fmaxf(acc[r]*INV16 + b2v, 0.f);
        _Float16 hi, lo;
        split_f16s(h, hi, lo);
        const int idx = (ks3*64 + qw*16 + mrow)*8 + jw;
        scr[0][idx] = hi;
        scr[1][idx] = lo;
      }
    }
    // read back this ptile's layer-3 A-fragments (same-wave DS ordering)
#pragma unroll
    for (int ks3 = 0; ks3 < 4; ++ks3) {
      const int base = (ks3*64 + l)*8;
      A3h[p][ks3] = *(const f16x8*)&scr[0][base];
      A3l[p][ks3] = *(const f16x8*)&scr[1][base];
    }
  }

  // ---- layer 3: nt-loop with B register ping-pong ----
  float* outp = out + ((size_t)b*NJ + j)*KF;
  f16x8 B0[2][4], B1[2][4];
  loadB3(B0, W3h, W3l, nt0, l);
  for (int k = 0; k < NT_PER; k += 2) {
    loadB3(B1, W3h, W3l, nt0 + k + 1, l);
    l3_body(A3h, A3l, B0, nt0 + k, l, b3, outp);
    if (k + 2 < NT_PER) loadB3(B0, W3h, W3l, nt0 + k + 2, l);
    l3_body(A3h, A3l, B1, nt0 + k + 1, l, b3, outp);
  }
}

// ---------------- pinv / update / loss (verified) ----------------
__global__ void pinv_kernel(const float* __restrict__ feats, const float* __restrict__ dt,
                            float* __restrict__ pinv) {
  int b = blockIdx.x, t = threadIdx.x;
  const float* f0 = feats + (size_t)b*7*KF;
  const float* fj = f0 + KF;
  float idt[6];
#pragma unroll
  for (int i = 0; i < 6; ++i) idt[i] = 1.f / dt[i];
  float H[21];
#pragma unroll
  for (int i = 0; i < 21; ++i) H[i] = 0.f;
  for (int k = t; k < KF; k += 256) {
    float f0k = f0[k];
    float Jk[6];
#pragma unroll
    for (int i = 0; i < 6; ++i) Jk[i] = (f0k - fj[i*KF + k]) * idt[i];
    int idx = 0;
#pragma unroll
    for (int i = 0; i < 6; ++i)
#pragma unroll
      for (int jj = i; jj < 6; ++jj) H[idx++] += Jk[i]*Jk[jj];
  }
  __shared__ float red[256*21];
#pragma unroll
  for (int i = 0; i < 21; ++i) red[t*21+i] = H[i];
  __syncthreads();
  for (int s = 128; s > 0; s >>= 1) {
    if (t < s)
      for (int i = 0; i < 21; ++i) red[t*21+i] += red[(t+s)*21+i];
    __syncthreads();
  }
  __shared__ float s_hinv[36];
  if (t == 0) {
    double A[6][12];
    int idx = 0;
    for (int i = 0; i < 6; ++i)
      for (int jj = i; jj < 6; ++jj) { A[i][jj] = red[idx]; A[jj][i] = red[idx]; idx++; }
    for (int i = 0; i < 6; ++i)
      for (int jj = 0; jj < 6; ++jj) A[i][6+jj] = (i == jj) ? 1.0 : 0.0;
    for (int col = 0; col < 6; ++col) {
      int piv = col; double best = fabs(A[col][col]);
      for (int r2 = col+1; r2 < 6; ++r2) {
        double v = fabs(A[r2][col]);
        if (v > best) { best = v; piv = r2; }
      }
      if (piv != col)
        for (int jj = 0; jj < 12; ++jj) { double tmp = A[col][jj]; A[col][jj] = A[piv][jj]; A[piv][jj] = tmp; }
      double inv = 1.0 / A[col][col];
      for (int jj = 0; jj < 12; ++jj) A[col][jj] *= inv;
      for (int r2 = 0; r2 < 6; ++r2) if (r2 != col) {
        double f = A[r2][col];
        for (int jj = 0; jj < 12; ++jj) A[r2][jj] -= f * A[col][jj];
      }
    }
    for (int i = 0; i < 6; ++i)
      for (int jj = 0; jj < 6; ++jj) s_hinv[i*6+jj] = (float)A[i][6+jj];
  }
  __syncthreads();
  for (int k = t; k < KF; k += 256) {
    float f0k = f0[k];
    float Jk[6];
#pragma unroll
    for (int i = 0; i < 6; ++i) Jk[i] = (f0k - fj[i*KF + k]) * idt[i];
#pragma unroll
    for (int i = 0; i < 6; ++i) {
      float s = 0.f;
#pragma unroll
      for (int jj = 0; jj < 6; ++jj) s += s_hinv[i*6+jj] * Jk[jj];
      pinv[((size_t)b*6 + i)*KF + k] = s;
    }
  }
}

__global__ void update_kernel(const float* __restrict__ feats, const float* __restrict__ f1,
                              const float* __restrict__ pinv, float* __restrict__ g_buf,
                              const float* __restrict__ W1, const float* __restrict__ b1,
                              float* __restrict__ W1effL, float* __restrict__ b1effL,
                              float* __restrict__ f1r, float* __restrict__ r_out,
                              const float* __restrict__ mean_tgt, const float* __restrict__ mean_src,
                              float* __restrict__ est_g, int final_it) {
  int b = blockIdx.x, t = threadIdx.x;
  const float* f0  = feats + (size_t)b*7*KF;
  const float* f1b = f1 + (size_t)b*KF;
  float acc[6] = {0.f,0.f,0.f,0.f,0.f,0.f};
  for (int k = t; k < KF; k += 256) {
    float r = f1b[k] - f0[k];
    r_out[(size_t)b*KF + k] = r;
#pragma unroll
    for (int i = 0; i < 6; ++i) acc[i] += pinv[((size_t)b*6+i)*KF + k] * r;
  }
  __shared__ float red[256*6];
#pragma unroll
  for (int i = 0; i < 6; ++i) red[t*6+i] = acc[i];
  __syncthreads();
  for (int s = 128; s > 0; s >>= 1) {
    if (t < s)
      for (int i = 0; i < 6; ++i) red[t*6+i] += red[(t+s)*6+i];
    __syncthreads();
  }
  __shared__ float s_g[16];
  if (t == 0) {
    float dx[6];
#pragma unroll
    for (int i = 0; i < 6; ++i) dx[i] = -red[i];
    float R[9], p[3];
    se3_exp_dev(dx, R, p);
    float* g = g_buf + b*16;
    float gn[16];
    for (int r2 = 0; r2 < 3; ++r2)
      for (int c = 0; c < 4; ++c)
        gn[r2*4+c] = R[r2*3+0]*g[c] + R[r2*3+1]*g[4+c] + R[r2*3+2]*g[8+c] + p[r2]*g[12+c];
    gn[12] = 0.f; gn[13] = 0.f; gn[14] = 0.f; gn[15] = 1.f;
    for (int i = 0; i < 16; ++i) { g[i] = gn[i]; s_g[i] = gn[i]; }
    if (final_it) {
      const float* p0m = mean_tgt + b*3;
      const float* p1m = mean_src + b*3;
      float* e = est_g + b*12;
      for (int r2 = 0; r2 < 3; ++r2) {
        e[r2*4+0] = gn[r2*4+0];
        e[r2*4+1] = gn[r2*4+1];
        e[r2*4+2] = gn[r2*4+2];
        e[r2*4+3] = gn[r2*4+3]
                  - (gn[r2*4+0]*p1m[0] + gn[r2*4+1]*p1m[1] + gn[r2*4+2]*p1m[2])
                  + p0m[r2];
      }
    }
  }
  __syncthreads();
  if (!final_it) {
    for (int i = t; i < 192; i += 256) {
      int d = i >> 6, c = i & 63;
      W1effL[b*192 + i] = s_g[0*4+d]*W1[c] + s_g[1*4+d]*W1[64+c] + s_g[2*4+d]*W1[128+c];
    }
    for (int i = t; i < 64; i += 256)
      b1effL[b*64 + i] = b1[i] + s_g[3]*W1[i] + s_g[7]*W1[64+i] + s_g[11]*W1[128+i];
    for (int k = t; k < KF; k += 256) f1r[(size_t)b*KF + k] = -INFINITY;
  }
}

__global__ void loss_kernel(const float* __restrict__ p_src, const float* __restrict__ est_g,
                            const float* __restrict__ igt_inv, float* __restrict__ loss_out) {
  int b = blockIdx.y, tile = blockIdx.x, t = threadIdx.x;
  int n = tile*256 + t;
  const float* e = est_g + b*12;
  const float* v = igt_inv + b*12;
  const float* p = p_src + ((size_t)b*NPTS + n)*3;
  float px = p[0], py = p[1], pz = p[2];
  float s = 0.f;
#pragma unroll
  for (int r2 = 0; r2 < 3; ++r2) {
    float d1 = e[r2*4+0]*px + e[r2*4+1]*py + e[r2*4+2]*pz + e[r2*4+3];
    float d2 = v[r2*4+0]*px + v[r2*4+1]*py + v[r2*4+2]*pz + v[r2*4+3];
    s += fabsf(d1 - d2);
  }
  __shared__ float red[256];
  red[t] = s;
  __syncthreads();
  for (int st = 128; st > 0; st >>= 1) {
    if (t < st) red[t] += red[t+st];
    __syncthreads();
  }
  if (t == 0) atomicAdd(loss_out, red[0] * (1.f/((float)BATCH*NPTS*3)));
}

// ---------------- launcher ----------------
extern "C" void kernel_launch(void* const* d_in, const int* in_sizes, int n_in,
                              void* d_out, int out_size, void* d_ws, size_t ws_size,
                              hipStream_t stream) {
  const float* p_src     = (const float*)d_in[0];
  const float* p_tgt     = (const float*)d_in[1];
  const float* igt_twist = (const float*)d_in[2];
  const float* dt        = (const float*)d_in[3];
  const float* W1        = (const float*)d_in[4];
  const float* b1        = (const float*)d_in[5];
  const float* W2        = (const float*)d_in[6];
  const float* b2        = (const float*)d_in[7];
  const float* W3        = (const float*)d_in[8];
  const float* b3        = (const float*)d_in[9];
  float* out = (float*)d_out;

  float* ws = (float*)d_ws;
  float* mean_tgt = ws;  ws += 32;   // BATCH*3 used
  float* mean_src = ws;  ws += 32;
  float* W1eff7   = ws;  ws += 7*192;
  float* b1eff7   = ws;  ws += 7*64;
  float* feats    = ws;  ws += BATCH*7*KF;
  float* W1effL   = ws;  ws += BATCH*192;
  float* b1effL   = ws;  ws += BATCH*64;
  float* f1       = ws;  ws += BATCH*KF;
  float* g_buf    = ws;  ws += BATCH*16;
  float* pinvb    = ws;  ws += BATCH*6*KF;
  float* igt_inv  = ws;  ws += 96;   // BATCH*12
  float* est_g    = ws;  ws += 96;   // BATCH*12
  _Float16* W2h = (_Float16*)ws;  ws += 8192/2;
  _Float16* W2l = (_Float16*)ws;  ws += 8192/2;
  _Float16* W3h = (_Float16*)ws;  ws += 131072/2;
  _Float16* W3l = (_Float16*)ws;  ws += 131072/2;

  float* r_out    = out;
  float* loss_out = out + BATCH*KF;

  means_kernel<<<dim3(BATCH*2), 256, 0, stream>>>(p_tgt, p_src, mean_tgt, mean_src);
  setup_kernel<<<1, 256, 0, stream>>>(dt, W1, b1, igt_twist, feats, f1, W1eff7, b1eff7,
                                      W1effL, b1effL, g_buf, igt_inv, loss_out);
  pack_w2_kernel<<<dim3(8192/256), 256, 0, stream>>>(W2, W2h, W2l);
  pack_w3_kernel<<<dim3(131072/256), 256, 0, stream>>>(W3, W3h, W3l);

  // f0 + 6 twist-perturbed encodes: FG=1 -> grid (64,7,8) = 3584 single-wave blocks
  encode_mfma<<<dim3(NPTS/PTW, 7, BATCH), 64, 0, stream>>>(
      p_tgt, mean_tgt, W1eff7, b1eff7, W2h, W2l, W3h, W3l, b2, b3, feats, 7, 1, 0);
  pinv_kernel<<<dim3(BATCH), 256, 0, stream>>>(feats, dt, pinvb);

  for (int it = 0; it < 5; ++it) {
    // loop encode: FG=4 -> grid (64,4,8) = 2048 single-wave blocks, NT_PER=16
    encode_mfma<<<dim3(NPTS/PTW, 4, BATCH), 64, 0, stream>>>(
        p_src, mean_src, W1effL, b1effL, W2h, W2l, W3h, W3l, b2, b3, f1, 1, 4, 1);
    update_kernel<<<dim3(BATCH), 256, 0, stream>>>(
        feats, f1, pinvb, g_buf, W1, b1, W1effL, b1effL, f1, r_out,
        mean_tgt, mean_src, est_g, (it == 4) ? 1 : 0);
  }
  loss_kernel<<<dim3(NPTS/256, BATCH), 256, 0, stream>>>(p_src, est_g, igt_inv, loss_out);
}